// Round 3
// baseline (5663.563 us; speedup 1.0000x reference)
//
#include <hip/hip_runtime.h>
#include <hip/hip_bf16.h>
#include <hip/hip_fp16.h>

#define FDIM 128
#define NCHUNK 8
#define CF 16   // features per chunk (32B fp16, 64B fp32)

typedef float f4 __attribute__((ext_vector_type(4)));
typedef float f2v __attribute__((ext_vector_type(2)));

// ---------- degree / dinv ----------

__global__ void degree_kernel(const int* __restrict__ col, int* __restrict__ deg, int E) {
    int e = blockIdx.x * blockDim.x + threadIdx.x;
    if (e < E) atomicAdd(&deg[col[e]], 1);
}

__global__ void dinv_kernel(const int* __restrict__ deg, float* __restrict__ dinv, int N) {
    int i = blockIdx.x * blockDim.x + threadIdx.x;
    if (i < N) {
        int d = deg[i];
        dinv[i] = (d > 0) ? rsqrtf((float)d) : 0.0f;
    }
}

// ---------- exclusive scan of deg -> rowptr ----------

__global__ void scan_blocks_kernel(const int* __restrict__ deg, int* __restrict__ rowptr,
                                   int* __restrict__ bsum, int N) {
    __shared__ int s[256];
    int t = threadIdx.x;
    int i = blockIdx.x * 256 + t;
    int v = (i < N) ? deg[i] : 0;
    s[t] = v;
    __syncthreads();
    for (int off = 1; off < 256; off <<= 1) {
        int add = (t >= off) ? s[t - off] : 0;
        __syncthreads();
        s[t] += add;
        __syncthreads();
    }
    if (i < N) rowptr[i] = s[t] - v;
    if (t == 255) bsum[blockIdx.x] = s[255];
}

__global__ void scan_bsums_kernel(int* __restrict__ bsum, int* __restrict__ boff, int nb) {
    __shared__ int s[512];
    int t = threadIdx.x;
    int v = (t < nb) ? bsum[t] : 0;
    s[t] = v;
    __syncthreads();
    for (int off = 1; off < 512; off <<= 1) {
        int add = (t >= off) ? s[t - off] : 0;
        __syncthreads();
        s[t] += add;
        __syncthreads();
    }
    if (t < nb) boff[t] = s[t] - v;
}

__global__ void add_offsets_kernel(int* __restrict__ rowptr, int* __restrict__ cursor,
                                   const int* __restrict__ boff, int N, int E) {
    int i = blockIdx.x * blockDim.x + threadIdx.x;
    if (i < N) {
        int v = rowptr[i] + boff[i >> 8];
        rowptr[i] = v;
        cursor[i] = v;
    }
    if (i == 0) rowptr[N] = E;
}

// ---------- edge placement: CSR by destination ----------

__global__ void place_kernel(const int* __restrict__ row, const int* __restrict__ col,
                             const float* __restrict__ dinv, int* __restrict__ cursor,
                             float2* __restrict__ edata, int E) {
    int e = blockIdx.x * blockDim.x + threadIdx.x;
    if (e < E) {
        int r = row[e], c = col[e];
        float w = dinv[r] * dinv[c];
        int pos = atomicAdd(&cursor[c], 1);
        edata[pos] = make_float2(__int_as_float(r), w);
    }
}

// ---------- out = mf[0] * x ; hx = fp16(x) in CHUNKED layout ----------
// chunked fp16 layout: h[c][n][16] halves, c = f>>4.
// thread i handles linear elements [8i, 8i+8) -> one 16B half store.

__global__ void init_out_kernel(const float4* __restrict__ x, const float* __restrict__ mf,
                                float4* __restrict__ out, __half* __restrict__ hx,
                                int N, long n8) {
    long i = (long)blockIdx.x * blockDim.x + threadIdx.x;
    if (i < n8) {
        float w = mf[0];
        float4 a = x[2 * i];
        float4 b = x[2 * i + 1];
        out[2 * i]     = make_float4(w * a.x, w * a.y, w * a.z, w * a.w);
        out[2 * i + 1] = make_float4(w * b.x, w * b.y, w * b.z, w * b.w);
        __half2 h[4];
        h[0] = __floats2half2_rn(a.x, a.y);
        h[1] = __floats2half2_rn(a.z, a.w);
        h[2] = __floats2half2_rn(b.x, b.y);
        h[3] = __floats2half2_rn(b.z, b.w);
        // chunked address
        long n  = i >> 4;            // node (16 threads per node)
        int  f0 = (int)(i & 15) * 8; // first feature
        int  c  = f0 >> 4;           // chunk
        long haddr = ((long)c * N + n) * CF + (f0 & 15);
        *(f4*)(hx + haddr) = *(const f4*)h;
    }
}

// ---------- fused gather prop, feature-chunked, XCD-pinned ----------
// chunk = blockIdx.x & 7  -> lands on XCD (blockIdx.x % 8): each XCD gathers
// only from its own 3.2MB fp16 chunk (L2-resident; written by the same XCD
// last pass). Wave: eg = lane>>3 (8 edge groups), fg = lane&7 (8 feature
// lanes x 2 fp16 = 32B row-chunk). 8 edges per issue, unroll 4 -> 32 edges
// in flight. edata + fp32 streams are non-temporal so they don't evict the
// chunk.
// tgt[n][c*16+f] = scale * sum_e w_e * src[c][idx_e][f] + beta * prev2[...]
// tgth[c][n][f] = fp16(tgt)   ; out += coef * tgt

__global__ __launch_bounds__(256) void gather_prop_kernel(
        const float2* __restrict__ edata, const int* __restrict__ rowptr,
        const __half* __restrict__ src, const float* __restrict__ prev2,
        float* __restrict__ tgt, __half* __restrict__ tgth, float* __restrict__ out,
        const float* __restrict__ mf, const float* __restrict__ lap,
        int i_coef, float scale, float beta, int N) {
    const int c    = blockIdx.x & 7;                       // chunk -> XCD
    const int wave = threadIdx.x >> 6;
    const int lane = threadIdx.x & 63;
    const int eg   = lane >> 3;                            // edge group 0..7
    const int fg   = lane & 7;                             // feature lane 0..7
    const long cN  = (long)c * N;
    const float coef = mf[i_coef] * lap[i_coef - 1];

    int d0 = (blockIdx.x >> 3) * 32 + wave * 8;

    for (int di = 0; di < 8; ++di) {
        int d = d0 + di;
        if (d >= N) return;
        int begin = rowptr[d];
        int end   = rowptr[d + 1];

        float ax = 0.f, ay = 0.f;
        #pragma unroll 4
        for (int e0 = begin; e0 < end; e0 += 8) {
            int e = e0 + eg;
            float w = 0.f;
            int idx = 0;
            if (e < end) {
                f2v ed = __builtin_nontemporal_load((const f2v*)edata + e);
                idx = __float_as_int(ed.x);
                w = ed.y;
            }
            const __half2 v = *(const __half2*)(src + ((cN + idx) << 4) + (fg << 1));
            float2 vf = __half22float2(v);
            ax += w * vf.x;
            ay += w * vf.y;
        }

        // reduce the 8 edge groups (xor over lane bits 3,4,5)
        ax += __shfl_xor(ax, 8, 64);
        ay += __shfl_xor(ay, 8, 64);
        ax += __shfl_xor(ax, 16, 64);
        ay += __shfl_xor(ay, 16, 64);
        ax += __shfl_xor(ax, 32, 64);
        ay += __shfl_xor(ay, 32, 64);

        if (lane < 8) {
            long o = ((long)d << 7) + (c << 4) + (fg << 1);  // fp32 linear elem offset
            float rx, ry;
            if (beta != 0.f) {
                f2v p = __builtin_nontemporal_load((const f2v*)(prev2 + o));
                rx = scale * ax + beta * p.x;
                ry = scale * ay + beta * p.y;
            } else {
                rx = scale * ax;
                ry = scale * ay;
            }
            f2v t = {rx, ry};
            __builtin_nontemporal_store(t, (f2v*)(tgt + o));
            if (tgth) {
                // chunked shadow: cacheable store -> stays in this XCD's L2
                *(__half2*)(tgth + ((cN + d) << 4) + (fg << 1)) = __floats2half2_rn(rx, ry);
            }
            f2v ov = __builtin_nontemporal_load((const f2v*)(out + o));
            ov.x += coef * rx;
            ov.y += coef * ry;
            __builtin_nontemporal_store(ov, (f2v*)(out + o));
        }
    }
}

extern "C" void kernel_launch(void* const* d_in, const int* in_sizes, int n_in,
                              void* d_out, int out_size, void* d_ws, size_t ws_size,
                              hipStream_t stream) {
    const float* x   = (const float*)d_in[0];
    const float* mf  = (const float*)d_in[1];
    const float* lap = (const float*)d_in[2];
    const int*   ei  = (const int*)d_in[3];
    float* out = (float*)d_out;

    const int  K  = in_sizes[1] - 1;          // 10
    const long NF = (long)in_sizes[0];        // N*F
    const int  N  = (int)(NF / FDIM);         // 100000
    const int  E  = in_sizes[3] / 2;          // 3200000
    const int* row = ei;
    const int* col = ei + E;

    // workspace layout (~180 MB)
    char* wp = (char*)d_ws;
    float*  bufA   = (float*)wp;  wp += NF * sizeof(float);
    float*  bufB   = (float*)wp;  wp += NF * sizeof(float);
    __half* hbufA  = (__half*)wp; wp += NF * sizeof(__half);
    __half* hbufB  = (__half*)wp; wp += NF * sizeof(__half);
    float2* edata  = (float2*)wp; wp += (size_t)E * sizeof(float2);
    int*    rowptr = (int*)wp;    wp += (size_t)(N + 1) * sizeof(int);
    int*    cursor = (int*)wp;    wp += (size_t)N * sizeof(int);
    int*    deg    = (int*)wp;    wp += (size_t)N * sizeof(int);
    float*  dinv   = (float*)wp;  wp += (size_t)N * sizeof(float);
    int*    bsum   = (int*)wp;    wp += 512 * sizeof(int);
    int*    boff   = (int*)wp;    wp += 512 * sizeof(int);

    const int BT = 256;
    const long n8 = NF / 8;
    const int n8_blocks = (int)((n8 + BT - 1) / BT);
    const int e_blocks  = (E + BT - 1) / BT;
    const int n_blocks  = (N + BT - 1) / BT;

    // CSR build
    hipMemsetAsync(deg, 0, (size_t)N * sizeof(int), stream);
    degree_kernel<<<e_blocks, BT, 0, stream>>>(col, deg, E);
    dinv_kernel<<<n_blocks, BT, 0, stream>>>(deg, dinv, N);
    scan_blocks_kernel<<<n_blocks, BT, 0, stream>>>(deg, rowptr, bsum, N);
    scan_bsums_kernel<<<1, 512, 0, stream>>>(bsum, boff, n_blocks);
    add_offsets_kernel<<<n_blocks, BT, 0, stream>>>(rowptr, cursor, boff, N, E);
    place_kernel<<<e_blocks, BT, 0, stream>>>(row, col, dinv, cursor, edata, E);

    // out = mf0 * x ; hbufB = fp16(x) chunked  (hbufB free until i=2 writes it)
    init_out_kernel<<<n8_blocks, BT, 0, stream>>>((const float4*)x, mf, (float4*)out,
                                                  hbufB, N, n8);

    // grid: 8 chunks x (32 dsts per block); chunk = bid & 7 -> XCD pin
    const int g_blocks = 8 * ((N + 31) / 32);

    // P1 = prop(x) -> bufA (+hbufA) ; out += c1*P1   (gathers chunked fp16 x)
    gather_prop_kernel<<<g_blocks, BT, 0, stream>>>(edata, rowptr, hbufB, x,
                                                    bufA, hbufA, out, mf, lap,
                                                    1, 1.0f, 0.0f, N);
    // P_i = 2*prop(P_{i-1}) - P_{i-2} ; out += c_i*P_i   (gathers fp16 shadow)
    for (int i = 2; i <= K; ++i) {
        const __half* srch  = (i % 2 == 0) ? hbufA : hbufB;  // fp16(P_{i-1})
        float*        tgt   = (i % 2 == 0) ? bufB : bufA;    // P_i (overwrites P_{i-2})
        __half*       tgth  = (i % 2 == 0) ? hbufB : hbufA;
        const float*  prev2 = (i == 2) ? x : (const float*)tgt;
        if (i == K) tgth = nullptr;  // last shadow never gathered
        gather_prop_kernel<<<g_blocks, BT, 0, stream>>>(edata, rowptr, srch, prev2,
                                                        tgt, tgth, out, mf, lap,
                                                        i, 2.0f, -1.0f, N);
    }
}

// Round 4
// 4228.651 us; speedup vs baseline: 1.3393x; 1.3393x over previous
//
#include <hip/hip_runtime.h>
#include <hip/hip_bf16.h>
#include <hip/hip_fp16.h>

#define FDIM 128
#define CF 16   // features per chunk: 32B fp16 rows, 3.2MB chunk -> L2-resident

typedef float f4 __attribute__((ext_vector_type(4)));

// ---------- degree / dinv ----------

__global__ void degree_kernel(const int* __restrict__ col, int* __restrict__ deg, int E) {
    int e = blockIdx.x * blockDim.x + threadIdx.x;
    if (e < E) atomicAdd(&deg[col[e]], 1);
}

__global__ void dinv_kernel(const int* __restrict__ deg, float* __restrict__ dinv, int N) {
    int i = blockIdx.x * blockDim.x + threadIdx.x;
    if (i < N) {
        int d = deg[i];
        dinv[i] = (d > 0) ? rsqrtf((float)d) : 0.0f;
    }
}

// ---------- exclusive scan of deg -> rowptr ----------

__global__ void scan_blocks_kernel(const int* __restrict__ deg, int* __restrict__ rowptr,
                                   int* __restrict__ bsum, int N) {
    __shared__ int s[256];
    int t = threadIdx.x;
    int i = blockIdx.x * 256 + t;
    int v = (i < N) ? deg[i] : 0;
    s[t] = v;
    __syncthreads();
    for (int off = 1; off < 256; off <<= 1) {
        int add = (t >= off) ? s[t - off] : 0;
        __syncthreads();
        s[t] += add;
        __syncthreads();
    }
    if (i < N) rowptr[i] = s[t] - v;
    if (t == 255) bsum[blockIdx.x] = s[255];
}

__global__ void scan_bsums_kernel(int* __restrict__ bsum, int* __restrict__ boff, int nb) {
    __shared__ int s[512];
    int t = threadIdx.x;
    int v = (t < nb) ? bsum[t] : 0;
    s[t] = v;
    __syncthreads();
    for (int off = 1; off < 512; off <<= 1) {
        int add = (t >= off) ? s[t - off] : 0;
        __syncthreads();
        s[t] += add;
        __syncthreads();
    }
    if (t < nb) boff[t] = s[t] - v;
}

__global__ void add_offsets_kernel(int* __restrict__ rowptr, int* __restrict__ cursor,
                                   const int* __restrict__ boff, int N, int E) {
    int i = blockIdx.x * blockDim.x + threadIdx.x;
    if (i < N) {
        int v = rowptr[i] + boff[i >> 8];
        rowptr[i] = v;
        cursor[i] = v;
    }
    if (i == 0) rowptr[N] = E;
}

// ---------- edge placement: CSR by destination, index only ----------
// dinv[r] is folded into the fp16 shadow rows; dinv[c] applied at write time,
// so per-edge payload is just the 4B source index.

__global__ void place_kernel(const int* __restrict__ row, const int* __restrict__ col,
                             int* __restrict__ cursor, int* __restrict__ eidx, int E) {
    int e = blockIdx.x * blockDim.x + threadIdx.x;
    if (e < E) {
        int c = col[e];
        int pos = atomicAdd(&cursor[c], 1);
        eidx[pos] = row[e];
    }
}

// ---------- out = mf[0] * x ; hx = fp16(dinv[n] * x) in CHUNKED layout ----------
// chunked fp16 layout: h[c][n][16] halves, c = f>>4.
// thread i handles linear elements [8i, 8i+8) -> one 16B half store.

__global__ void init_out_kernel(const float4* __restrict__ x, const float* __restrict__ mf,
                                const float* __restrict__ dinv,
                                float4* __restrict__ out, __half* __restrict__ hx,
                                int N, long n8) {
    long i = (long)blockIdx.x * blockDim.x + threadIdx.x;
    if (i < n8) {
        float w = mf[0];
        float4 a = x[2 * i];
        float4 b = x[2 * i + 1];
        out[2 * i]     = make_float4(w * a.x, w * a.y, w * a.z, w * a.w);
        out[2 * i + 1] = make_float4(w * b.x, w * b.y, w * b.z, w * b.w);
        long n  = i >> 4;            // node (16 threads per node)
        int  f0 = (int)(i & 15) * 8; // first feature
        float dv = dinv[n];
        __half2 h[4];
        h[0] = __floats2half2_rn(dv * a.x, dv * a.y);
        h[1] = __floats2half2_rn(dv * a.z, dv * a.w);
        h[2] = __floats2half2_rn(dv * b.x, dv * b.y);
        h[3] = __floats2half2_rn(dv * b.z, dv * b.w);
        long haddr = ((long)(f0 >> 4) * N + n) * CF + (f0 & 8);
        *(f4*)(hx + haddr) = *(const f4*)h;
    }
}

// ---------- fused gather prop: feature-chunked, XCD-pinned, no reduction ----------
// chunk c = blockIdx.x & 7 -> XCD c: gathers hit this XCD's L2-resident 3.2MB
// shadow chunk (written by the same XCD last pass).
// Wave = 32 consecutive dsts x 2 feature-lanes. Lane (dloc, fg) walks dst
// d=base+dloc's edge list; one gather instruction = 64 lanes x 16B = 1KB
// covering 32 edge-rows of 32B. Loop runs to wave-max degree; masked lanes
// gather row 0 with weight 0 (L1-hit, cheap). No cross-lane reduction; all 64
// lanes write.
// P_i(d) = scale * dinv[d] * sum_e shadow[r_e] + beta * P_{i-2}(d)
// tgth[c][d][:] = fp16(dinv[d] * P_i(d))  ; out += coef * P_i(d)

__global__ __launch_bounds__(256) void gather_prop_kernel(
        const int* __restrict__ eidx, const int* __restrict__ rowptr,
        const float* __restrict__ dinv,
        const __half* __restrict__ src, const float* __restrict__ prev2,
        float* __restrict__ tgt, __half* __restrict__ tgth, float* __restrict__ out,
        const float* __restrict__ mf, const float* __restrict__ lap,
        int i_coef, float scale, float beta, int N) {
    const int c    = blockIdx.x & 7;           // chunk -> XCD
    const int wave = threadIdx.x >> 6;
    const int lane = threadIdx.x & 63;
    const int dloc = lane >> 1;                // dst within wave 0..31
    const int fg   = lane & 1;                 // feature half: 8 fp16 = 16B
    const long cN  = (long)c * N;

    int d = (blockIdx.x >> 3) * 128 + wave * 32 + dloc;
    bool valid = d < N;
    int begin = 0, nit = 0;
    if (valid) {
        begin = rowptr[d];
        nit   = rowptr[d + 1] - begin;
    }
    int maxit = nit;
    #pragma unroll
    for (int m = 2; m <= 32; m <<= 1)
        maxit = max(maxit, __shfl_xor(maxit, m, 64));

    float acc[8];
    #pragma unroll
    for (int j = 0; j < 8; ++j) acc[j] = 0.f;

    const __half* srcc = src + (cN << 4) + (fg << 3);

    #pragma unroll 4
    for (int k = 0; k < maxit; ++k) {
        int idx = 0;
        float wsel = 0.f;
        if (k < nit) {
            idx = eidx[begin + k];   // cacheable: line reused across 16 iters
            wsel = 1.f;
        }
        f4 raw = *(const f4*)(srcc + ((long)idx << 4));
        const __half2* h = (const __half2*)&raw;
        float2 f0 = __half22float2(h[0]);
        float2 f1 = __half22float2(h[1]);
        float2 f2 = __half22float2(h[2]);
        float2 f3 = __half22float2(h[3]);
        acc[0] += wsel * f0.x; acc[1] += wsel * f0.y;
        acc[2] += wsel * f1.x; acc[3] += wsel * f1.y;
        acc[4] += wsel * f2.x; acc[5] += wsel * f2.y;
        acc[6] += wsel * f3.x; acc[7] += wsel * f3.y;
    }

    if (!valid) return;

    float dv   = dinv[d];
    float sdv  = scale * dv;
    float coef = mf[i_coef] * lap[i_coef - 1];
    long  o    = ((long)d << 7) + (c << 4) + (fg << 3);  // fp32 linear elem offset

    float r[8];
    if (beta != 0.f) {
        f4 p0 = __builtin_nontemporal_load((const f4*)(prev2 + o));
        f4 p1 = __builtin_nontemporal_load((const f4*)(prev2 + o) + 1);
        r[0] = sdv * acc[0] + beta * p0.x;
        r[1] = sdv * acc[1] + beta * p0.y;
        r[2] = sdv * acc[2] + beta * p0.z;
        r[3] = sdv * acc[3] + beta * p0.w;
        r[4] = sdv * acc[4] + beta * p1.x;
        r[5] = sdv * acc[5] + beta * p1.y;
        r[6] = sdv * acc[6] + beta * p1.z;
        r[7] = sdv * acc[7] + beta * p1.w;
    } else {
        #pragma unroll
        for (int j = 0; j < 8; ++j) r[j] = sdv * acc[j];
    }
    f4 t0 = {r[0], r[1], r[2], r[3]};
    f4 t1 = {r[4], r[5], r[6], r[7]};
    __builtin_nontemporal_store(t0, (f4*)(tgt + o));
    __builtin_nontemporal_store(t1, (f4*)(tgt + o) + 1);
    if (tgth) {
        // chunked dinv-scaled shadow: cacheable -> stays in this XCD's L2
        __half2 hh[4];
        hh[0] = __floats2half2_rn(dv * r[0], dv * r[1]);
        hh[1] = __floats2half2_rn(dv * r[2], dv * r[3]);
        hh[2] = __floats2half2_rn(dv * r[4], dv * r[5]);
        hh[3] = __floats2half2_rn(dv * r[6], dv * r[7]);
        *(f4*)(tgth + ((cN + d) << 4) + (fg << 3)) = *(const f4*)hh;
    }
    f4 o0 = __builtin_nontemporal_load((const f4*)(out + o));
    f4 o1 = __builtin_nontemporal_load((const f4*)(out + o) + 1);
    o0.x += coef * r[0]; o0.y += coef * r[1]; o0.z += coef * r[2]; o0.w += coef * r[3];
    o1.x += coef * r[4]; o1.y += coef * r[5]; o1.z += coef * r[6]; o1.w += coef * r[7];
    __builtin_nontemporal_store(o0, (f4*)(out + o));
    __builtin_nontemporal_store(o1, (f4*)(out + o) + 1);
}

extern "C" void kernel_launch(void* const* d_in, const int* in_sizes, int n_in,
                              void* d_out, int out_size, void* d_ws, size_t ws_size,
                              hipStream_t stream) {
    const float* x   = (const float*)d_in[0];
    const float* mf  = (const float*)d_in[1];
    const float* lap = (const float*)d_in[2];
    const int*   ei  = (const int*)d_in[3];
    float* out = (float*)d_out;

    const int  K  = in_sizes[1] - 1;          // 10
    const long NF = (long)in_sizes[0];        // N*F
    const int  N  = (int)(NF / FDIM);         // 100000
    const int  E  = in_sizes[3] / 2;          // 3200000
    const int* row = ei;
    const int* col = ei + E;

    // workspace layout (~170 MB)
    char* wp = (char*)d_ws;
    float*  bufA   = (float*)wp;  wp += NF * sizeof(float);
    float*  bufB   = (float*)wp;  wp += NF * sizeof(float);
    __half* hbufA  = (__half*)wp; wp += NF * sizeof(__half);
    __half* hbufB  = (__half*)wp; wp += NF * sizeof(__half);
    int*    eidx   = (int*)wp;    wp += (size_t)E * sizeof(int);
    int*    rowptr = (int*)wp;    wp += (size_t)(N + 1) * sizeof(int);
    int*    cursor = (int*)wp;    wp += (size_t)N * sizeof(int);
    int*    deg    = (int*)wp;    wp += (size_t)N * sizeof(int);
    float*  dinv   = (float*)wp;  wp += (size_t)N * sizeof(float);
    int*    bsum   = (int*)wp;    wp += 512 * sizeof(int);
    int*    boff   = (int*)wp;    wp += 512 * sizeof(int);

    const int BT = 256;
    const long n8 = NF / 8;
    const int n8_blocks = (int)((n8 + BT - 1) / BT);
    const int e_blocks  = (E + BT - 1) / BT;
    const int n_blocks  = (N + BT - 1) / BT;

    // CSR build
    hipMemsetAsync(deg, 0, (size_t)N * sizeof(int), stream);
    degree_kernel<<<e_blocks, BT, 0, stream>>>(col, deg, E);
    dinv_kernel<<<n_blocks, BT, 0, stream>>>(deg, dinv, N);
    scan_blocks_kernel<<<n_blocks, BT, 0, stream>>>(deg, rowptr, bsum, N);
    scan_bsums_kernel<<<1, 512, 0, stream>>>(bsum, boff, n_blocks);
    add_offsets_kernel<<<n_blocks, BT, 0, stream>>>(rowptr, cursor, boff, N, E);
    place_kernel<<<e_blocks, BT, 0, stream>>>(row, col, cursor, eidx, E);

    // out = mf0 * x ; hbufB = fp16(dinv*x) chunked  (hbufB free until i=2)
    init_out_kernel<<<n8_blocks, BT, 0, stream>>>((const float4*)x, mf, dinv,
                                                  (float4*)out, hbufB, N, n8);

    // grid: 8 chunks x (128 dsts per block); chunk = bid & 7 -> XCD pin
    const int g_blocks = 8 * ((N + 127) / 128);

    // P1 = prop(x) -> bufA (+hbufA) ; out += c1*P1   (gathers chunked fp16 dinv*x)
    gather_prop_kernel<<<g_blocks, BT, 0, stream>>>(eidx, rowptr, dinv, hbufB, x,
                                                    bufA, hbufA, out, mf, lap,
                                                    1, 1.0f, 0.0f, N);
    // P_i = 2*prop(P_{i-1}) - P_{i-2} ; out += c_i*P_i   (gathers fp16 shadow)
    for (int i = 2; i <= K; ++i) {
        const __half* srch  = (i % 2 == 0) ? hbufA : hbufB;  // fp16(dinv*P_{i-1})
        float*        tgt   = (i % 2 == 0) ? bufB : bufA;    // P_i (overwrites P_{i-2})
        __half*       tgth  = (i % 2 == 0) ? hbufB : hbufA;
        const float*  prev2 = (i == 2) ? x : (const float*)tgt;
        if (i == K) tgth = nullptr;  // last shadow never gathered
        gather_prop_kernel<<<g_blocks, BT, 0, stream>>>(eidx, rowptr, dinv, srch, prev2,
                                                        tgt, tgth, out, mf, lap,
                                                        i, 2.0f, -1.0f, N);
    }
}